// Round 9
// baseline (390.346 us; speedup 1.0000x reference)
//
#include <hip/hip_runtime.h>
#include <hip/hip_bf16.h>

typedef __attribute__((ext_vector_type(8))) short bf16x8;
typedef __attribute__((ext_vector_type(4))) float f32x4;
typedef __attribute__((ext_vector_type(4))) unsigned int u32x4;
typedef __attribute__((ext_vector_type(2))) unsigned int u32x2;
typedef __attribute__((ext_vector_type(2))) __bf16 bf16x2v;

#define EPS 1e-5f

__device__ inline unsigned short f2bf(float x) {  // RNE (prep kernel only; cold)
  unsigned int u = __builtin_bit_cast(unsigned int, x);
  unsigned int r = (u + 0x7FFFu + ((u >> 16) & 1u)) >> 16;
  return (unsigned short)r;
}

// hot-path pair pack: compiles to v_cvt_pk_bf16_f32 (1 VALU op; RNE)
__device__ inline unsigned int cvtpk(float a, float b) {
  bf16x2v v = {(__bf16)a, (__bf16)b};
  return __builtin_bit_cast(unsigned int, v);
}

// ---------------- prep: fold BN, pre-swizzle W1/W2 into MFMA fragment order ----------------
// ws layout: w1f bf16 [73728 B] | w2f bf16 [16384 B] | sc f32[384]
// W2 rows permuted: physical k-slot s holds logical row (s&96)|((s&1)<<4)|((s>>1)&15)
// — matches the packed x1 writes.
__global__ void prep_kernel(const float* __restrict__ W1, const float* __restrict__ W2,
                            const float* __restrict__ b1, const float* __restrict__ g1,
                            const float* __restrict__ be1, const float* __restrict__ m1,
                            const float* __restrict__ v1,
                            const float* __restrict__ b2, const float* __restrict__ g2,
                            const float* __restrict__ be2, const float* __restrict__ m2,
                            const float* __restrict__ v2,
                            unsigned short* __restrict__ w1f, unsigned short* __restrict__ w2f,
                            float* __restrict__ sc) {
  int t = blockIdx.x * 256 + threadIdx.x;
  if (t < 36864) {
    int j = t & 7, l = (t >> 3) & 63, f = t >> 9;
    int kb = f >> 3, nb = f & 7;
    int rk = kb * 32 + ((l >> 4) << 3) + j;
    int cn = (nb << 4) + (l & 15);
    w1f[t] = f2bf(W1[rk * 128 + cn]);
  } else if (t < 45056) {
    int o = t - 36864;
    int j = o & 7, l = (o >> 3) & 63, f = o >> 9;
    int kb = f >> 2, nb = f & 3;
    int s = kb * 32 + ((l >> 4) << 3) + j;                 // physical k-slot
    int rk = (s & 96) | ((s & 1) << 4) | ((s >> 1) & 15);  // logical W2 row
    int cn = (nb << 4) + (l & 15);
    w2f[o] = f2bf(W2[rk * 64 + cn]);
  } else if (t < 45184) {
    int j = t - 45056;
    float s = g1[j] * rsqrtf(v1[j] + EPS);
    sc[j] = s;
    sc[128 + j] = (b1[j] - m1[j]) * s + be1[j];
  } else if (t < 45248) {
    int j = t - 45184;
    float s = g2[j] * rsqrtf(v2[j] + EPS);
    sc[256 + j] = s;
    sc[320 + j] = (b2[j] - m2[j]) * s + be2[j];
  }
}

// ---------------- fused main kernel (512 threads = 8 waves, 2/SIMD, 256-reg/wave cap) ----------------
// W1 (72 VGPR) register-resident -> zero W1 LDS reads; W2 in LDS (16 KB, staged once).
// __launch_bounds__(512) with NO min-occupancy arg: R7/R8 evidence shows the 2nd arg
// is applied as min-BLOCKS (2 blocks x 8 waves -> 128-reg cap -> spill). Block size
// alone already caps regs at 256/wave (8 waves must fit the 2048-reg pool).
// LDS map:
//   [0, 81920)        A-tile [128 rows x 640 B], XOR-swizzled
//   [81920, 114688)   x1 [128 rows x 256 B], XOR-swizzled, k-permuted (pairs packed)
//   [114688, 131072)  W2 frags (persistent)
//   [131072, 132096)  l3 f32[256]
#define LDS_X1_OFF 81920
#define LDS_W2_OFF 114688
#define LDS_L3_OFF 131072
#define LDS_TOTAL 132096

// macros, not lambdas (R3: reference-captured lambdas forced locals to scratch)
#define WRITE_A()                                                                                \
  do {                                                                                           \
    const int rswz_ = (sr & 7) << 4;                                                             \
    char* rowp_ = AR + sr * 640;                                                                 \
    u32x4 s0_ = {cvtpk(sv0[0], sv0[1]), cvtpk(sv0[2], sv0[3]), cvtpk(sv1[0], sv1[1]),            \
                 cvtpk(sv1[2], sv1[3])};                                                         \
    u32x4 s1_ = {cvtpk(sv2[0], sv2[1]), cvtpk(sv2[2], sv2[3]), cvtpk(sv3[0], sv3[1]),            \
                 cvtpk(sv3[2], sv3[3])};                                                         \
    u32x4 d0_ = {cvtpk(dv0[0], dv0[1]), cvtpk(dv0[2], dv0[3]), cvtpk(dv1[0], dv1[1]),            \
                 cvtpk(dv1[2], dv1[3])};                                                         \
    u32x4 d1_ = {cvtpk(dv2[0], dv2[1]), cvtpk(dv2[2], dv2[3]), cvtpk(dv3[0], dv3[1]),            \
                 cvtpk(dv3[2], dv3[3])};                                                         \
    u32x4 p0_ = {cvtpk(sv0[0] * dv0[0], sv0[1] * dv0[1]), cvtpk(sv0[2] * dv0[2], sv0[3] * dv0[3]),\
                 cvtpk(sv1[0] * dv1[0], sv1[1] * dv1[1]), cvtpk(sv1[2] * dv1[2], sv1[3] * dv1[3])};\
    u32x4 p1_ = {cvtpk(sv2[0] * dv2[0], sv2[1] * dv2[1]), cvtpk(sv2[2] * dv2[2], sv2[3] * dv2[3]),\
                 cvtpk(sv3[0] * dv3[0], sv3[1] * dv3[1]), cvtpk(sv3[2] * dv3[2], sv3[3] * dv3[3])};\
    u32x4 a0_ = {cvtpk(fabsf(sv0[0] - dv0[0]), fabsf(sv0[1] - dv0[1])),                          \
                 cvtpk(fabsf(sv0[2] - dv0[2]), fabsf(sv0[3] - dv0[3])),                          \
                 cvtpk(fabsf(sv1[0] - dv1[0]), fabsf(sv1[1] - dv1[1])),                          \
                 cvtpk(fabsf(sv1[2] - dv1[2]), fabsf(sv1[3] - dv1[3]))};                         \
    u32x4 a1_ = {cvtpk(fabsf(sv2[0] - dv2[0]), fabsf(sv2[1] - dv2[1])),                          \
                 cvtpk(fabsf(sv2[2] - dv2[2]), fabsf(sv2[3] - dv2[3])),                          \
                 cvtpk(fabsf(sv3[0] - dv3[0]), fabsf(sv3[1] - dv3[1])),                          \
                 cvtpk(fabsf(sv3[2] - dv3[2]), fabsf(sv3[3] - dv3[3]))};                         \
    u32x4 c0_ = {cvtpk(cv0[0], cv0[1]), cvtpk(cv0[2], cv0[3]), cvtpk(cv1[0], cv1[1]),            \
                 cvtpk(cv1[2], cv1[3])};                                                         \
    *(u32x4*)(rowp_ + ((sh * 32) ^ rswz_)) = s0_;                                                \
    *(u32x4*)(rowp_ + ((sh * 32 + 16) ^ rswz_)) = s1_;                                           \
    *(u32x4*)(rowp_ + ((128 + sh * 32) ^ rswz_)) = d0_;                                          \
    *(u32x4*)(rowp_ + ((128 + sh * 32 + 16) ^ rswz_)) = d1_;                                     \
    *(u32x4*)(rowp_ + ((256 + sh * 32) ^ rswz_)) = p0_;                                          \
    *(u32x4*)(rowp_ + ((256 + sh * 32 + 16) ^ rswz_)) = p1_;                                     \
    *(u32x4*)(rowp_ + ((384 + sh * 32) ^ rswz_)) = a0_;                                          \
    *(u32x4*)(rowp_ + ((384 + sh * 32 + 16) ^ rswz_)) = a1_;                                     \
    *(u32x4*)(rowp_ + ((512 + sh * 16) ^ rswz_)) = c0_;                                          \
  } while (0)

#define GATHER_NEXT(tg)                                                                          \
  do {                                                                                           \
    const f32x4* zs_ = (const f32x4*)(z + ((size_t)i0n * 64 + sh * 16));                         \
    sv0 = zs_[0]; sv1 = zs_[1]; sv2 = zs_[2]; sv3 = zs_[3];                                      \
    const f32x4* zd_ = (const f32x4*)(z + ((size_t)i1n * 64 + sh * 16));                         \
    dv0 = zd_[0]; dv1 = zd_[1]; dv2 = zd_[2]; dv3 = zd_[3];                                      \
    int eg_ = ((tg) << 7) + sr;                                                                  \
    int esg_ = eg_ < E ? eg_ : E - 1;                                                            \
    const f32x4* cx_ = (const f32x4*)(ctx + (size_t)esg_ * 32 + sh * 8);                         \
    cv0 = cx_[0]; cv1 = cx_[1];                                                                  \
    int tn_ = (tg) + grid;                                                                       \
    if (tn_ >= nblk) tn_ = (tg);                                                                 \
    int en_ = (tn_ << 7) + sr;                                                                   \
    int esn_ = en_ < E ? en_ : E - 1;                                                            \
    i0n = ei[esn_];                                                                              \
    i1n = ei[E + esn_];                                                                          \
  } while (0)

#define MFMA16(A, B, C) __builtin_amdgcn_mfma_f32_16x16x32_bf16((A), (B), (C), 0, 0, 0)

#define L1STEP(KB, BB0, BB1)                                                                     \
  do {                                                                                           \
    bf16x8 a0_ = *(const bf16x8*)(ap0 + (((KB) * 64 + g * 16) ^ aswz));                          \
    bf16x8 a1_ = *(const bf16x8*)(ap1 + (((KB) * 64 + g * 16) ^ aswz));                          \
    bf16x8 a2_ = *(const bf16x8*)(ap2 + (((KB) * 64 + g * 16) ^ aswz));                          \
    bf16x8 a3_ = *(const bf16x8*)(ap3 + (((KB) * 64 + g * 16) ^ aswz));                          \
    acc00 = MFMA16(a0_, BB0, acc00); acc01 = MFMA16(a0_, BB1, acc01);                            \
    acc10 = MFMA16(a1_, BB0, acc10); acc11 = MFMA16(a1_, BB1, acc11);                            \
    acc20 = MFMA16(a2_, BB0, acc20); acc21 = MFMA16(a2_, BB1, acc21);                            \
    acc30 = MFMA16(a3_, BB0, acc30); acc31 = MFMA16(a3_, BB1, acc31);                            \
  } while (0)

#define X1W(MF, ACA, ACB)                                                                        \
  do {                                                                                           \
    _Pragma("unroll")                                                                            \
    for (int j = 0; j < 4; j++) {                                                                \
      int row_ = wr * 64 + (MF) * 16 + 4 * g + j;                                                \
      unsigned int p_ = cvtpk(fmaxf(ACA[j] * s1v0 + c1v0, 0.f),                                  \
                              fmaxf(ACB[j] * s1v1 + c1v1, 0.f));                                 \
      *(unsigned int*)(X1 + row_ * 256 + (xoff ^ ((row_ & 7) << 4))) = p_;                       \
    }                                                                                            \
  } while (0)

#define L2STEP(KB)                                                                               \
  do {                                                                                           \
    bf16x8 xa_ = *(const bf16x8*)(xp0 + (((KB) * 64 + g * 16) ^ aswz));                          \
    bf16x8 xb_ = *(const bf16x8*)(xp1 + (((KB) * 64 + g * 16) ^ aswz));                          \
    bf16x8 bg_ = *(const bf16x8*)(W2L + (((KB) * 4 + w2c * 2 + 0) * 64 + lane) * 16);            \
    bf16x8 bh_ = *(const bf16x8*)(W2L + (((KB) * 4 + w2c * 2 + 1) * 64 + lane) * 16);            \
    acc2A0 = MFMA16(xa_, bg_, acc2A0); acc2A1 = MFMA16(xa_, bh_, acc2A1);                        \
    acc2B0 = MFMA16(xb_, bg_, acc2B0); acc2B1 = MFMA16(xb_, bh_, acc2B1);                        \
  } while (0)

__global__ __launch_bounds__(512) void fused_kernel(
    const float* __restrict__ z, const int* __restrict__ ei, const float* __restrict__ ctx,
    const unsigned short* __restrict__ w1f, const unsigned short* __restrict__ w2f,
    const float* __restrict__ sc, const float* __restrict__ w3, const float* __restrict__ b3,
    float* __restrict__ out, int E, int nblk) {
  extern __shared__ char lds[];
  char* AR = lds;
  char* X1 = lds + LDS_X1_OFF;
  char* W2L = lds + LDS_W2_OFF;
  float* l3 = (float*)(lds + LDS_L3_OFF);

  const int tid = threadIdx.x;
  const int lane = tid & 63, wave = tid >> 6;       // 8 waves
  const int g = lane >> 4, lq = lane & 15;
  const int wr = wave >> 2, wc = wave & 3;          // L1 grid 2x4: 64 rows x 32 cols per wave
  const int w2r = wave >> 1, w2c = wave & 1;        // L2 grid 4x2: 32 rows x 32 cols per wave
  const int sr = tid >> 2, sh = tid & 3;            // staging: 4 threads per edge
  const int grid = gridDim.x;
  const int aswz = (lq & 7) << 4;

  // ---- stage W2 frags into LDS (16 KB, persistent) ----
  ((f32x4*)W2L)[tid] = ((const f32x4*)w2f)[tid];
  ((f32x4*)W2L)[512 + tid] = ((const f32x4*)w2f)[512 + tid];

  // ---- hoist BN/W3 constants into registers (global loads, once) ----
  const int col0 = wc * 32 + lq;
  const float s1v0 = sc[col0], c1v0 = sc[128 + col0];
  const float s1v1 = sc[col0 + 16], c1v1 = sc[128 + col0 + 16];
  const int colA = w2c * 32 + lq;
  const float s2A = sc[256 + colA], c2A = sc[320 + colA];
  const float s2B = sc[256 + colA + 16], c2B = sc[320 + colA + 16];
  const float w3A = w3[colA], w3B = w3[colA + 16];
  const float b3v = b3[0];
  const int xoff = wc * 64 + lq * 4;  // packed x1 pair slots (perm matches prep W2)

  // ---- persistent W1 fragments in registers (72 VGPR): nf = wc*2 + {0,1}, kb 0..8 ----
  const bf16x8* W1G = (const bf16x8*)w1f;
  bf16x8 w1r0 = W1G[(0 * 8 + wc * 2 + 0) * 64 + lane], w1s0 = W1G[(0 * 8 + wc * 2 + 1) * 64 + lane];
  bf16x8 w1r1 = W1G[(1 * 8 + wc * 2 + 0) * 64 + lane], w1s1 = W1G[(1 * 8 + wc * 2 + 1) * 64 + lane];
  bf16x8 w1r2 = W1G[(2 * 8 + wc * 2 + 0) * 64 + lane], w1s2 = W1G[(2 * 8 + wc * 2 + 1) * 64 + lane];
  bf16x8 w1r3 = W1G[(3 * 8 + wc * 2 + 0) * 64 + lane], w1s3 = W1G[(3 * 8 + wc * 2 + 1) * 64 + lane];
  bf16x8 w1r4 = W1G[(4 * 8 + wc * 2 + 0) * 64 + lane], w1s4 = W1G[(4 * 8 + wc * 2 + 1) * 64 + lane];
  bf16x8 w1r5 = W1G[(5 * 8 + wc * 2 + 0) * 64 + lane], w1s5 = W1G[(5 * 8 + wc * 2 + 1) * 64 + lane];
  bf16x8 w1r6 = W1G[(6 * 8 + wc * 2 + 0) * 64 + lane], w1s6 = W1G[(6 * 8 + wc * 2 + 1) * 64 + lane];
  bf16x8 w1r7 = W1G[(7 * 8 + wc * 2 + 0) * 64 + lane], w1s7 = W1G[(7 * 8 + wc * 2 + 1) * 64 + lane];
  bf16x8 w1r8 = W1G[(8 * 8 + wc * 2 + 0) * 64 + lane], w1s8 = W1G[(8 * 8 + wc * 2 + 1) * 64 + lane];

  f32x4 sv0, sv1, sv2, sv3, dv0, dv1, dv2, dv3, cv0, cv1;
  int i0n, i1n;
  int t = blockIdx.x;

  // ---- prologue: gather tile t, write A(t), gather t+1, prefetch ei t+2 ----
  {
    int e = (t << 7) + sr;
    int es = e < E ? e : E - 1;
    int a0 = ei[es], a1 = ei[E + es];
    const f32x4* cx = (const f32x4*)(ctx + (size_t)es * 32 + sh * 8);
    cv0 = cx[0]; cv1 = cx[1];
    const f32x4* zs = (const f32x4*)(z + ((size_t)a0 * 64 + sh * 16));
    sv0 = zs[0]; sv1 = zs[1]; sv2 = zs[2]; sv3 = zs[3];
    const f32x4* zd = (const f32x4*)(z + ((size_t)a1 * 64 + sh * 16));
    dv0 = zd[0]; dv1 = zd[1]; dv2 = zd[2]; dv3 = zd[3];
    int tn = t + grid;
    if (tn >= nblk) tn = t;
    int en = (tn << 7) + sr;
    int esn = en < E ? en : E - 1;
    i0n = ei[esn];
    i1n = ei[E + esn];
  }
  WRITE_A();
  {
    int tn = t + grid;
    if (tn >= nblk) tn = t;
    GATHER_NEXT(tn);
  }
  __syncthreads();  // A(t) + W2L visible

  for (; t < nblk; t += grid) {
    // ---- layer 1: A[128x288] @ W1[288x128]; wave tile 64x32 (4x2 frags), W1 from regs ----
    f32x4 acc00 = {0.f, 0.f, 0.f, 0.f}, acc01 = acc00, acc10 = acc00, acc11 = acc00;
    f32x4 acc20 = acc00, acc21 = acc00, acc30 = acc00, acc31 = acc00;
    const char* ap0 = AR + (wr * 64 + 0 * 16 + lq) * 640;
    const char* ap1 = AR + (wr * 64 + 1 * 16 + lq) * 640;
    const char* ap2 = AR + (wr * 64 + 2 * 16 + lq) * 640;
    const char* ap3 = AR + (wr * 64 + 3 * 16 + lq) * 640;
    L1STEP(0, w1r0, w1s0);
    L1STEP(1, w1r1, w1s1);
    L1STEP(2, w1r2, w1s2);
    L1STEP(3, w1r3, w1s3);
    L1STEP(4, w1r4, w1s4);
    L1STEP(5, w1r5, w1s5);
    L1STEP(6, w1r6, w1s6);
    L1STEP(7, w1r7, w1s7);
    L1STEP(8, w1r8, w1s8);
    __syncthreads();  // all waves done reading A(t)

    // ---- phase 2: A-write(t+1), issue gathers(t+2), x1-write(t) ----
    WRITE_A();  // consumes t+1 gather regs
    {
      int tn2 = t + 2 * grid;
      if (tn2 >= nblk) tn2 = t + grid < nblk ? t + grid : t;
      GATHER_NEXT(tn2);  // long-latency loads; land during next phases
    }
    X1W(0, acc00, acc01);
    X1W(1, acc10, acc11);
    X1W(2, acc20, acc21);
    X1W(3, acc30, acc31);
    __syncthreads();  // x1(t) + A(t+1) visible

    // ---- layer 2: x1[128x128] @ W2[128x64]; wave tile 32x32 (2x2 frags), W2 from LDS ----
    f32x4 acc2A0 = {0.f, 0.f, 0.f, 0.f}, acc2A1 = acc2A0, acc2B0 = acc2A0, acc2B1 = acc2A0;
    const char* xp0 = X1 + (w2r * 32 + lq) * 256;
    const char* xp1 = xp0 + 4096;
    L2STEP(0);
    L2STEP(1);
    L2STEP(2);
    L2STEP(3);

    // ---- layer 3: bn+relu, dot w3, 16-lane shfl reduce ----
    {
#pragma unroll
      for (int j = 0; j < 4; j++) {
        float pA = fmaxf(acc2A0[j] * s2A + c2A, 0.f) * w3A +
                   fmaxf(acc2A1[j] * s2B + c2B, 0.f) * w3B;
        pA += __shfl_xor(pA, 1);
        pA += __shfl_xor(pA, 2);
        pA += __shfl_xor(pA, 4);
        pA += __shfl_xor(pA, 8);
        float pB = fmaxf(acc2B0[j] * s2A + c2A, 0.f) * w3A +
                   fmaxf(acc2B1[j] * s2B + c2B, 0.f) * w3B;
        pB += __shfl_xor(pB, 1);
        pB += __shfl_xor(pB, 2);
        pB += __shfl_xor(pB, 4);
        pB += __shfl_xor(pB, 8);
        if (lq == 0) {
          l3[(w2r * 32 + 4 * g + j) * 2 + w2c] = pA;
          l3[(w2r * 32 + 16 + 4 * g + j) * 2 + w2c] = pB;
        }
      }
    }
    __syncthreads();  // l3 visible; all x1 reads done

    // ---- out(t): l3 not rewritten until two barriers from now -> safe ----
    if (tid < 128) {
      int e = (t << 7) + tid;
      if (e < E) out[e] = l3[tid * 2] + l3[tid * 2 + 1] + b3v;
    }
  }
}

extern "C" void kernel_launch(void* const* d_in, const int* in_sizes, int n_in,
                              void* d_out, int out_size, void* d_ws, size_t ws_size,
                              hipStream_t stream) {
  const float* z = (const float*)d_in[0];
  const int* ei = (const int*)d_in[1];
  const float* ctx = (const float*)d_in[2];
  const float* W1 = (const float*)d_in[3];
  const float* b1 = (const float*)d_in[4];
  const float* g1 = (const float*)d_in[5];
  const float* be1 = (const float*)d_in[6];
  const float* m1 = (const float*)d_in[7];
  const float* v1 = (const float*)d_in[8];
  const float* W2 = (const float*)d_in[9];
  const float* b2 = (const float*)d_in[10];
  const float* g2 = (const float*)d_in[11];
  const float* be2 = (const float*)d_in[12];
  const float* m2 = (const float*)d_in[13];
  const float* v2 = (const float*)d_in[14];
  const float* W3 = (const float*)d_in[15];
  const float* b3 = (const float*)d_in[16];
  float* out = (float*)d_out;
  const int E = out_size;

  unsigned short* w1f = (unsigned short*)d_ws;
  unsigned short* w2f = (unsigned short*)((char*)d_ws + 73728);
  float* sc = (float*)((char*)d_ws + 90112);

  prep_kernel<<<177, 256, 0, stream>>>(W1, W2, b1, g1, be1, m1, v1,
                                       b2, g2, be2, m2, v2, w1f, w2f, sc);

  const int nblk = (E + 127) >> 7;
  (void)hipFuncSetAttribute((const void*)fused_kernel,
                            hipFuncAttributeMaxDynamicSharedMemorySize, LDS_TOTAL);
  fused_kernel<<<256, 512, LDS_TOTAL, stream>>>(z, ei, ctx, w1f, w2f, sc, W3, b3,
                                                out, E, nblk);
}

// Round 10
// 137.184 us; speedup vs baseline: 2.8454x; 2.8454x over previous
//
#include <hip/hip_runtime.h>
#include <hip/hip_bf16.h>

typedef __attribute__((ext_vector_type(8))) short bf16x8;
typedef __attribute__((ext_vector_type(4))) float f32x4;
typedef __attribute__((ext_vector_type(4))) unsigned int u32x4;
typedef __attribute__((ext_vector_type(2))) unsigned int u32x2;
typedef __attribute__((ext_vector_type(2))) __bf16 bf16x2v;

#define EPS 1e-5f

__device__ inline unsigned short f2bf(float x) {  // RNE (prep kernel only; cold)
  unsigned int u = __builtin_bit_cast(unsigned int, x);
  unsigned int r = (u + 0x7FFFu + ((u >> 16) & 1u)) >> 16;
  return (unsigned short)r;
}

// hot-path pair pack: compiles to v_cvt_pk_bf16_f32 (1 VALU op; RNE)
__device__ inline unsigned int cvtpk(float a, float b) {
  bf16x2v v = {(__bf16)a, (__bf16)b};
  return __builtin_bit_cast(unsigned int, v);
}

// ---------------- prep: fold BN, pre-swizzle W1/W2 into MFMA fragment order ----------------
// ws layout: w1f bf16 [73728 B] | w2f bf16 [16384 B] | sc f32[384]
// W2 rows permuted: physical k-slot s holds logical row (s&96)|((s&1)<<4)|((s>>1)&15)
// — matches the packed x1 writes.
__global__ void prep_kernel(const float* __restrict__ W1, const float* __restrict__ W2,
                            const float* __restrict__ b1, const float* __restrict__ g1,
                            const float* __restrict__ be1, const float* __restrict__ m1,
                            const float* __restrict__ v1,
                            const float* __restrict__ b2, const float* __restrict__ g2,
                            const float* __restrict__ be2, const float* __restrict__ m2,
                            const float* __restrict__ v2,
                            unsigned short* __restrict__ w1f, unsigned short* __restrict__ w2f,
                            float* __restrict__ sc) {
  int t = blockIdx.x * 256 + threadIdx.x;
  if (t < 36864) {
    int j = t & 7, l = (t >> 3) & 63, f = t >> 9;
    int kb = f >> 3, nb = f & 7;
    int rk = kb * 32 + ((l >> 4) << 3) + j;
    int cn = (nb << 4) + (l & 15);
    w1f[t] = f2bf(W1[rk * 128 + cn]);
  } else if (t < 45056) {
    int o = t - 36864;
    int j = o & 7, l = (o >> 3) & 63, f = o >> 9;
    int kb = f >> 2, nb = f & 3;
    int s = kb * 32 + ((l >> 4) << 3) + j;                 // physical k-slot
    int rk = (s & 96) | ((s & 1) << 4) | ((s >> 1) & 15);  // logical W2 row
    int cn = (nb << 4) + (l & 15);
    w2f[o] = f2bf(W2[rk * 64 + cn]);
  } else if (t < 45184) {
    int j = t - 45056;
    float s = g1[j] * rsqrtf(v1[j] + EPS);
    sc[j] = s;
    sc[128 + j] = (b1[j] - m1[j]) * s + be1[j];
  } else if (t < 45248) {
    int j = t - 45184;
    float s = g2[j] * rsqrtf(v2[j] + EPS);
    sc[256 + j] = s;
    sc[320 + j] = (b2[j] - m2[j]) * s + be2[j];
  }
}

// ================= PRIMARY: 512 threads, W1 in regs, __launch_bounds__(512,1) =================
// Evidence R5-R9: (1024,4)->64 regs, (512,2)->128, (512)->128 — 2nd arg behaves as
// min-BLOCKS (or default 4 waves/EU floor). (512,1) yields a 256-reg cap under either
// semantics (block residency alone bounds at 256). Host code checks localSizeBytes
// (spill) and falls back to the proven 1024-thr kernel if the grant didn't happen.
// LDS map:
//   [0, 81920)        A-tile [128 rows x 640 B], XOR-swizzled
//   [81920, 114688)   x1 [128 rows x 256 B], XOR-swizzled, k-permuted (pairs packed)
//   [114688, 131072)  W2 frags (persistent)
//   [131072, 132096)  l3 f32[256]
#define R_X1_OFF 81920
#define R_W2_OFF 114688
#define R_L3_OFF 131072
#define R_LDS_TOTAL 132096

#define WRITE_A_R()                                                                              \
  do {                                                                                           \
    const int rswz_ = (sr & 7) << 4;                                                             \
    char* rowp_ = AR + sr * 640;                                                                 \
    u32x4 s0_ = {cvtpk(sv0[0], sv0[1]), cvtpk(sv0[2], sv0[3]), cvtpk(sv1[0], sv1[1]),            \
                 cvtpk(sv1[2], sv1[3])};                                                         \
    u32x4 s1_ = {cvtpk(sv2[0], sv2[1]), cvtpk(sv2[2], sv2[3]), cvtpk(sv3[0], sv3[1]),            \
                 cvtpk(sv3[2], sv3[3])};                                                         \
    u32x4 d0_ = {cvtpk(dv0[0], dv0[1]), cvtpk(dv0[2], dv0[3]), cvtpk(dv1[0], dv1[1]),            \
                 cvtpk(dv1[2], dv1[3])};                                                         \
    u32x4 d1_ = {cvtpk(dv2[0], dv2[1]), cvtpk(dv2[2], dv2[3]), cvtpk(dv3[0], dv3[1]),            \
                 cvtpk(dv3[2], dv3[3])};                                                         \
    u32x4 p0_ = {cvtpk(sv0[0] * dv0[0], sv0[1] * dv0[1]), cvtpk(sv0[2] * dv0[2], sv0[3] * dv0[3]),\
                 cvtpk(sv1[0] * dv1[0], sv1[1] * dv1[1]), cvtpk(sv1[2] * dv1[2], sv1[3] * dv1[3])};\
    u32x4 p1_ = {cvtpk(sv2[0] * dv2[0], sv2[1] * dv2[1]), cvtpk(sv2[2] * dv2[2], sv2[3] * dv2[3]),\
                 cvtpk(sv3[0] * dv3[0], sv3[1] * dv3[1]), cvtpk(sv3[2] * dv3[2], sv3[3] * dv3[3])};\
    u32x4 a0_ = {cvtpk(fabsf(sv0[0] - dv0[0]), fabsf(sv0[1] - dv0[1])),                          \
                 cvtpk(fabsf(sv0[2] - dv0[2]), fabsf(sv0[3] - dv0[3])),                          \
                 cvtpk(fabsf(sv1[0] - dv1[0]), fabsf(sv1[1] - dv1[1])),                          \
                 cvtpk(fabsf(sv1[2] - dv1[2]), fabsf(sv1[3] - dv1[3]))};                         \
    u32x4 a1_ = {cvtpk(fabsf(sv2[0] - dv2[0]), fabsf(sv2[1] - dv2[1])),                          \
                 cvtpk(fabsf(sv2[2] - dv2[2]), fabsf(sv2[3] - dv2[3])),                          \
                 cvtpk(fabsf(sv3[0] - dv3[0]), fabsf(sv3[1] - dv3[1])),                          \
                 cvtpk(fabsf(sv3[2] - dv3[2]), fabsf(sv3[3] - dv3[3]))};                         \
    u32x4 c0_ = {cvtpk(cv0[0], cv0[1]), cvtpk(cv0[2], cv0[3]), cvtpk(cv1[0], cv1[1]),            \
                 cvtpk(cv1[2], cv1[3])};                                                         \
    *(u32x4*)(rowp_ + ((sh * 32) ^ rswz_)) = s0_;                                                \
    *(u32x4*)(rowp_ + ((sh * 32 + 16) ^ rswz_)) = s1_;                                           \
    *(u32x4*)(rowp_ + ((128 + sh * 32) ^ rswz_)) = d0_;                                          \
    *(u32x4*)(rowp_ + ((128 + sh * 32 + 16) ^ rswz_)) = d1_;                                     \
    *(u32x4*)(rowp_ + ((256 + sh * 32) ^ rswz_)) = p0_;                                          \
    *(u32x4*)(rowp_ + ((256 + sh * 32 + 16) ^ rswz_)) = p1_;                                     \
    *(u32x4*)(rowp_ + ((384 + sh * 32) ^ rswz_)) = a0_;                                          \
    *(u32x4*)(rowp_ + ((384 + sh * 32 + 16) ^ rswz_)) = a1_;                                     \
    *(u32x4*)(rowp_ + ((512 + sh * 16) ^ rswz_)) = c0_;                                          \
  } while (0)

#define GATHER_NEXT_R(tg)                                                                        \
  do {                                                                                           \
    const f32x4* zs_ = (const f32x4*)(z + ((size_t)i0n * 64 + sh * 16));                         \
    sv0 = zs_[0]; sv1 = zs_[1]; sv2 = zs_[2]; sv3 = zs_[3];                                      \
    const f32x4* zd_ = (const f32x4*)(z + ((size_t)i1n * 64 + sh * 16));                         \
    dv0 = zd_[0]; dv1 = zd_[1]; dv2 = zd_[2]; dv3 = zd_[3];                                      \
    int eg_ = ((tg) << 7) + sr;                                                                  \
    int esg_ = eg_ < E ? eg_ : E - 1;                                                            \
    const f32x4* cx_ = (const f32x4*)(ctx + (size_t)esg_ * 32 + sh * 8);                         \
    cv0 = cx_[0]; cv1 = cx_[1];                                                                  \
    int tn_ = (tg) + grid;                                                                       \
    if (tn_ >= nblk) tn_ = (tg);                                                                 \
    int en_ = (tn_ << 7) + sr;                                                                   \
    int esn_ = en_ < E ? en_ : E - 1;                                                            \
    i0n = ei[esn_];                                                                              \
    i1n = ei[E + esn_];                                                                          \
  } while (0)

#define MFMA16(A, B, C) __builtin_amdgcn_mfma_f32_16x16x32_bf16((A), (B), (C), 0, 0, 0)

#define L1STEP_R(KB, BB0, BB1)                                                                   \
  do {                                                                                           \
    bf16x8 a0_ = *(const bf16x8*)(ap0 + (((KB) * 64 + g * 16) ^ aswz));                          \
    bf16x8 a1_ = *(const bf16x8*)(ap1 + (((KB) * 64 + g * 16) ^ aswz));                          \
    bf16x8 a2_ = *(const bf16x8*)(ap2 + (((KB) * 64 + g * 16) ^ aswz));                          \
    bf16x8 a3_ = *(const bf16x8*)(ap3 + (((KB) * 64 + g * 16) ^ aswz));                          \
    acc00 = MFMA16(a0_, BB0, acc00); acc01 = MFMA16(a0_, BB1, acc01);                            \
    acc10 = MFMA16(a1_, BB0, acc10); acc11 = MFMA16(a1_, BB1, acc11);                            \
    acc20 = MFMA16(a2_, BB0, acc20); acc21 = MFMA16(a2_, BB1, acc21);                            \
    acc30 = MFMA16(a3_, BB0, acc30); acc31 = MFMA16(a3_, BB1, acc31);                            \
  } while (0)

#define X1W_R(MF, ACA, ACB)                                                                      \
  do {                                                                                           \
    _Pragma("unroll")                                                                            \
    for (int j = 0; j < 4; j++) {                                                                \
      int row_ = wr * 64 + (MF) * 16 + 4 * g + j;                                                \
      unsigned int p_ = cvtpk(fmaxf(ACA[j] * s1v0 + c1v0, 0.f),                                  \
                              fmaxf(ACB[j] * s1v1 + c1v1, 0.f));                                 \
      *(unsigned int*)(X1 + row_ * 256 + (xoff ^ ((row_ & 7) << 4))) = p_;                       \
    }                                                                                            \
  } while (0)

#define L2STEP_R(KB)                                                                             \
  do {                                                                                           \
    bf16x8 xa_ = *(const bf16x8*)(xp0 + (((KB) * 64 + g * 16) ^ aswz));                          \
    bf16x8 xb_ = *(const bf16x8*)(xp1 + (((KB) * 64 + g * 16) ^ aswz));                          \
    bf16x8 bg_ = *(const bf16x8*)(W2L + (((KB) * 4 + w2c * 2 + 0) * 64 + lane) * 16);            \
    bf16x8 bh_ = *(const bf16x8*)(W2L + (((KB) * 4 + w2c * 2 + 1) * 64 + lane) * 16);            \
    acc2A0 = MFMA16(xa_, bg_, acc2A0); acc2A1 = MFMA16(xa_, bh_, acc2A1);                        \
    acc2B0 = MFMA16(xb_, bg_, acc2B0); acc2B1 = MFMA16(xb_, bh_, acc2B1);                        \
  } while (0)

__global__ __launch_bounds__(512, 1) void fused_kernel_r(
    const float* __restrict__ z, const int* __restrict__ ei, const float* __restrict__ ctx,
    const unsigned short* __restrict__ w1f, const unsigned short* __restrict__ w2f,
    const float* __restrict__ sc, const float* __restrict__ w3, const float* __restrict__ b3,
    float* __restrict__ out, int E, int nblk) {
  extern __shared__ char lds[];
  char* AR = lds;
  char* X1 = lds + R_X1_OFF;
  char* W2L = lds + R_W2_OFF;
  float* l3 = (float*)(lds + R_L3_OFF);

  const int tid = threadIdx.x;
  const int lane = tid & 63, wave = tid >> 6;       // 8 waves
  const int g = lane >> 4, lq = lane & 15;
  const int wr = wave >> 2, wc = wave & 3;          // L1 grid 2x4: 64 rows x 32 cols per wave
  const int w2r = wave >> 1, w2c = wave & 1;        // L2 grid 4x2: 32 rows x 32 cols per wave
  const int sr = tid >> 2, sh = tid & 3;            // staging: 4 threads per edge
  const int grid = gridDim.x;
  const int aswz = (lq & 7) << 4;

  // ---- stage W2 frags into LDS (16 KB, persistent) ----
  ((f32x4*)W2L)[tid] = ((const f32x4*)w2f)[tid];
  ((f32x4*)W2L)[512 + tid] = ((const f32x4*)w2f)[512 + tid];

  // ---- hoist BN/W3 constants into registers (global loads, once) ----
  const int col0 = wc * 32 + lq;
  const float s1v0 = sc[col0], c1v0 = sc[128 + col0];
  const float s1v1 = sc[col0 + 16], c1v1 = sc[128 + col0 + 16];
  const int colA = w2c * 32 + lq;
  const float s2A = sc[256 + colA], c2A = sc[320 + colA];
  const float s2B = sc[256 + colA + 16], c2B = sc[320 + colA + 16];
  const float w3A = w3[colA], w3B = w3[colA + 16];
  const float b3v = b3[0];
  const int xoff = wc * 64 + lq * 4;  // packed x1 pair slots (perm matches prep W2)

  // ---- persistent W1 fragments in registers (72 VGPR): nf = wc*2 + {0,1}, kb 0..8 ----
  const bf16x8* W1G = (const bf16x8*)w1f;
  bf16x8 w1r0 = W1G[(0 * 8 + wc * 2 + 0) * 64 + lane], w1s0 = W1G[(0 * 8 + wc * 2 + 1) * 64 + lane];
  bf16x8 w1r1 = W1G[(1 * 8 + wc * 2 + 0) * 64 + lane], w1s1 = W1G[(1 * 8 + wc * 2 + 1) * 64 + lane];
  bf16x8 w1r2 = W1G[(2 * 8 + wc * 2 + 0) * 64 + lane], w1s2 = W1G[(2 * 8 + wc * 2 + 1) * 64 + lane];
  bf16x8 w1r3 = W1G[(3 * 8 + wc * 2 + 0) * 64 + lane], w1s3 = W1G[(3 * 8 + wc * 2 + 1) * 64 + lane];
  bf16x8 w1r4 = W1G[(4 * 8 + wc * 2 + 0) * 64 + lane], w1s4 = W1G[(4 * 8 + wc * 2 + 1) * 64 + lane];
  bf16x8 w1r5 = W1G[(5 * 8 + wc * 2 + 0) * 64 + lane], w1s5 = W1G[(5 * 8 + wc * 2 + 1) * 64 + lane];
  bf16x8 w1r6 = W1G[(6 * 8 + wc * 2 + 0) * 64 + lane], w1s6 = W1G[(6 * 8 + wc * 2 + 1) * 64 + lane];
  bf16x8 w1r7 = W1G[(7 * 8 + wc * 2 + 0) * 64 + lane], w1s7 = W1G[(7 * 8 + wc * 2 + 1) * 64 + lane];
  bf16x8 w1r8 = W1G[(8 * 8 + wc * 2 + 0) * 64 + lane], w1s8 = W1G[(8 * 8 + wc * 2 + 1) * 64 + lane];

  f32x4 sv0, sv1, sv2, sv3, dv0, dv1, dv2, dv3, cv0, cv1;
  int i0n, i1n;
  int t = blockIdx.x;

  // ---- prologue: gather tile t, write A(t), gather t+1, prefetch ei t+2 ----
  {
    int e = (t << 7) + sr;
    int es = e < E ? e : E - 1;
    int a0 = ei[es], a1 = ei[E + es];
    const f32x4* cx = (const f32x4*)(ctx + (size_t)es * 32 + sh * 8);
    cv0 = cx[0]; cv1 = cx[1];
    const f32x4* zs = (const f32x4*)(z + ((size_t)a0 * 64 + sh * 16));
    sv0 = zs[0]; sv1 = zs[1]; sv2 = zs[2]; sv3 = zs[3];
    const f32x4* zd = (const f32x4*)(z + ((size_t)a1 * 64 + sh * 16));
    dv0 = zd[0]; dv1 = zd[1]; dv2 = zd[2]; dv3 = zd[3];
    int tn = t + grid;
    if (tn >= nblk) tn = t;
    int en = (tn << 7) + sr;
    int esn = en < E ? en : E - 1;
    i0n = ei[esn];
    i1n = ei[E + esn];
  }
  WRITE_A_R();
  {
    int tn = t + grid;
    if (tn >= nblk) tn = t;
    GATHER_NEXT_R(tn);
  }
  __syncthreads();  // A(t) + W2L visible

  for (; t < nblk; t += grid) {
    // ---- layer 1: A[128x288] @ W1[288x128]; wave tile 64x32 (4x2 frags), W1 from regs ----
    f32x4 acc00 = {0.f, 0.f, 0.f, 0.f}, acc01 = acc00, acc10 = acc00, acc11 = acc00;
    f32x4 acc20 = acc00, acc21 = acc00, acc30 = acc00, acc31 = acc00;
    const char* ap0 = AR + (wr * 64 + 0 * 16 + lq) * 640;
    const char* ap1 = AR + (wr * 64 + 1 * 16 + lq) * 640;
    const char* ap2 = AR + (wr * 64 + 2 * 16 + lq) * 640;
    const char* ap3 = AR + (wr * 64 + 3 * 16 + lq) * 640;
    L1STEP_R(0, w1r0, w1s0);
    L1STEP_R(1, w1r1, w1s1);
    L1STEP_R(2, w1r2, w1s2);
    L1STEP_R(3, w1r3, w1s3);
    L1STEP_R(4, w1r4, w1s4);
    L1STEP_R(5, w1r5, w1s5);
    L1STEP_R(6, w1r6, w1s6);
    L1STEP_R(7, w1r7, w1s7);
    L1STEP_R(8, w1r8, w1s8);
    __syncthreads();  // all waves done reading A(t)

    // ---- phase 2: A-write(t+1), issue gathers(t+2), x1-write(t) ----
    WRITE_A_R();
    {
      int tn2 = t + 2 * grid;
      if (tn2 >= nblk) tn2 = t + grid < nblk ? t + grid : t;
      GATHER_NEXT_R(tn2);
    }
    X1W_R(0, acc00, acc01);
    X1W_R(1, acc10, acc11);
    X1W_R(2, acc20, acc21);
    X1W_R(3, acc30, acc31);
    __syncthreads();  // x1(t) + A(t+1) visible

    // ---- layer 2: x1[128x128] @ W2[128x64]; wave tile 32x32, W2 from LDS ----
    f32x4 acc2A0 = {0.f, 0.f, 0.f, 0.f}, acc2A1 = acc2A0, acc2B0 = acc2A0, acc2B1 = acc2A0;
    const char* xp0 = X1 + (w2r * 32 + lq) * 256;
    const char* xp1 = xp0 + 4096;
    L2STEP_R(0);
    L2STEP_R(1);
    L2STEP_R(2);
    L2STEP_R(3);

    // ---- layer 3: bn+relu, dot w3, 16-lane shfl reduce ----
    {
#pragma unroll
      for (int j = 0; j < 4; j++) {
        float pA = fmaxf(acc2A0[j] * s2A + c2A, 0.f) * w3A +
                   fmaxf(acc2A1[j] * s2B + c2B, 0.f) * w3B;
        pA += __shfl_xor(pA, 1);
        pA += __shfl_xor(pA, 2);
        pA += __shfl_xor(pA, 4);
        pA += __shfl_xor(pA, 8);
        float pB = fmaxf(acc2B0[j] * s2A + c2A, 0.f) * w3A +
                   fmaxf(acc2B1[j] * s2B + c2B, 0.f) * w3B;
        pB += __shfl_xor(pB, 1);
        pB += __shfl_xor(pB, 2);
        pB += __shfl_xor(pB, 4);
        pB += __shfl_xor(pB, 8);
        if (lq == 0) {
          l3[(w2r * 32 + 4 * g + j) * 2 + w2c] = pA;
          l3[(w2r * 32 + 16 + 4 * g + j) * 2 + w2c] = pB;
        }
      }
    }
    __syncthreads();  // l3 visible; all x1 reads done

    if (tid < 128) {
      int e = (t << 7) + tid;
      if (e < E) out[e] = l3[tid * 2] + l3[tid * 2 + 1] + b3v;
    }
  }
}

// ================= FALLBACK: R6 kernel verbatim (137.7 us, no spill) =================
// 1024 threads, W1 in LDS, W2 in regs (32 VGPR), SC in LDS, X1 aliases A region.
#define F_SC_OFF 73728
#define F_A_OFF 75776
#define F_L3_OFF 157696
#define F_LDS_TOTAL 158720

#define WRITE_A_F()                                                                              \
  do {                                                                                           \
    const int rswz_ = (sr & 7) << 4;                                                             \
    char* rowp_ = AR + sr * 640;                                                                 \
    u32x4 ps_ = {cvtpk(sv0[0], sv0[1]), cvtpk(sv0[2], sv0[3]), cvtpk(sv1[0], sv1[1]),            \
                 cvtpk(sv1[2], sv1[3])};                                                         \
    u32x4 pd_ = {cvtpk(dv0[0], dv0[1]), cvtpk(dv0[2], dv0[3]), cvtpk(dv1[0], dv1[1]),            \
                 cvtpk(dv1[2], dv1[3])};                                                         \
    u32x4 pp_ = {cvtpk(sv0[0] * dv0[0], sv0[1] * dv0[1]), cvtpk(sv0[2] * dv0[2], sv0[3] * dv0[3]),\
                 cvtpk(sv1[0] * dv1[0], sv1[1] * dv1[1]), cvtpk(sv1[2] * dv1[2], sv1[3] * dv1[3])};\
    u32x4 pa_ = {cvtpk(fabsf(sv0[0] - dv0[0]), fabsf(sv0[1] - dv0[1])),                          \
                 cvtpk(fabsf(sv0[2] - dv0[2]), fabsf(sv0[3] - dv0[3])),                          \
                 cvtpk(fabsf(sv1[0] - dv1[0]), fabsf(sv1[1] - dv1[1])),                          \
                 cvtpk(fabsf(sv1[2] - dv1[2]), fabsf(sv1[3] - dv1[3]))};                         \
    u32x2 pc_ = {cvtpk(cv[0], cv[1]), cvtpk(cv[2], cv[3])};                                      \
    *(u32x4*)(rowp_ + ((sh * 16) ^ rswz_)) = ps_;                                                \
    *(u32x4*)(rowp_ + ((128 + sh * 16) ^ rswz_)) = pd_;                                          \
    *(u32x4*)(rowp_ + ((256 + sh * 16) ^ rswz_)) = pp_;                                          \
    *(u32x4*)(rowp_ + ((384 + sh * 16) ^ rswz_)) = pa_;                                          \
    *(u32x2*)(rowp_ + 512 + ((sh * 8) ^ rswz_)) = pc_;                                           \
  } while (0)

#define GATHER_NEXT_F(tg)                                                                        \
  do {                                                                                           \
    const f32x4* zs_ = (const f32x4*)(z + ((size_t)i0n * 64 + sh * 8));                          \
    sv0 = zs_[0];                                                                                \
    sv1 = zs_[1];                                                                                \
    const f32x4* zd_ = (const f32x4*)(z + ((size_t)i1n * 64 + sh * 8));                          \
    dv0 = zd_[0];                                                                                \
    dv1 = zd_[1];                                                                                \
    int eg_ = ((tg) << 7) + sr;                                                                  \
    int esg_ = eg_ < E ? eg_ : E - 1;                                                            \
    cv = *(const f32x4*)(ctx + (size_t)esg_ * 32 + sh * 4);                                      \
    int tn_ = (tg) + grid;                                                                       \
    if (tn_ >= nblk) tn_ = (tg);                                                                 \
    int en_ = (tn_ << 7) + sr;                                                                   \
    int esn_ = en_ < E ? en_ : E - 1;                                                            \
    i0n = ei[esn_];                                                                              \
    i1n = ei[E + esn_];                                                                          \
  } while (0)

__global__ __launch_bounds__(1024, 4) void fused_kernel_f(
    const float* __restrict__ z, const int* __restrict__ ei, const float* __restrict__ ctx,
    const unsigned short* __restrict__ w1f, const unsigned short* __restrict__ w2f,
    const float* __restrict__ sc, const float* __restrict__ w3, const float* __restrict__ b3,
    float* __restrict__ out, int E, int nblk) {
  extern __shared__ char lds[];
  char* W1L = lds;
  float* SC = (float*)(lds + F_SC_OFF);
  char* AR = lds + F_A_OFF;
  char* X1 = lds + F_A_OFF;  // alias: x1 overwrites A-head after L1 reads complete
  float* l3 = (float*)(lds + F_L3_OFF);

  const int tid = threadIdx.x;
  const int lane = tid & 63, wave = tid >> 6;
  const int g = lane >> 4, lq = lane & 15;
  const int wr = wave >> 2, wc = wave & 3;   // L1 grid 4x4
  const int w2r = wave >> 1, w2c = wave & 1; // L2 grid 8x2
  const int sr = tid >> 3, sh = tid & 7;     // staging: 8 threads per edge
  const int grid = gridDim.x;

  {
    const f32x4* s = (const f32x4*)w1f;
    f32x4* d = (f32x4*)W1L;
#pragma unroll
    for (int i = 0; i < 4; i++) d[i * 1024 + tid] = s[i * 1024 + tid];
    if (tid < 512) d[4096 + tid] = s[4096 + tid];
    if (tid < 128) {
      SC[tid] = sc[tid];
      SC[128 + tid] = sc[128 + tid];
    } else if (tid < 192) {
      int j = tid - 128;
      SC[256 + j] = sc[256 + j];
      SC[320 + j] = sc[320 + j];
      SC[384 + j] = w3[j];
    } else if (tid == 192) {
      SC[448] = b3[0];
    }
  }

  bf16x8 w2g0, w2g1, w2g2, w2g3, w2h0, w2h1, w2h2, w2h3;
  {
    const bf16x8* W2G = (const bf16x8*)w2f;
    w2g0 = W2G[(0 * 4 + w2c * 2 + 0) * 64 + lane];
    w2h0 = W2G[(0 * 4 + w2c * 2 + 1) * 64 + lane];
    w2g1 = W2G[(1 * 4 + w2c * 2 + 0) * 64 + lane];
    w2h1 = W2G[(1 * 4 + w2c * 2 + 1) * 64 + lane];
    w2g2 = W2G[(2 * 4 + w2c * 2 + 0) * 64 + lane];
    w2h2 = W2G[(2 * 4 + w2c * 2 + 1) * 64 + lane];
    w2g3 = W2G[(3 * 4 + w2c * 2 + 0) * 64 + lane];
    w2h3 = W2G[(3 * 4 + w2c * 2 + 1) * 64 + lane];
  }

  f32x4 sv0, sv1, dv0, dv1, cv;
  int i0n, i1n;
  int t = blockIdx.x;

  {
    int e = (t << 7) + sr;
    int es = e < E ? e : E - 1;
    int a0 = ei[es], a1 = ei[E + es];
    cv = *(const f32x4*)(ctx + (size_t)es * 32 + sh * 4);
    const f32x4* zs = (const f32x4*)(z + ((size_t)a0 * 64 + sh * 8));
    sv0 = zs[0];
    sv1 = zs[1];
    const f32x4* zd = (const f32x4*)(z + ((size_t)a1 * 64 + sh * 8));
    dv0 = zd[0];
    dv1 = zd[1];
    int tn = t + grid;
    if (tn >= nblk) tn = t;
    int en = (tn << 7) + sr;
    int esn = en < E ? en : E - 1;
    i0n = ei[esn];
    i1n = ei[E + esn];
  }
  WRITE_A_F();
  {
    int tn = t + grid;
    if (tn >= nblk) tn = t;
    GATHER_NEXT_F(tn);
  }
  __syncthreads();

  for (; t < nblk; t += grid) {
    f32x4 acc00 = {0.f, 0.f, 0.f, 0.f}, acc01 = acc00, acc10 = acc00, acc11 = acc00;
    const bf16x8* W1F = (const bf16x8*)W1L;
    const int row0 = wr * 32 + lq, row1 = row0 + 16;
    const int swz0 = (row0 & 7) << 4, swz1 = (row1 & 7) << 4;
    const char* ap0 = AR + row0 * 640;
    const char* ap1 = AR + row1 * 640;
#pragma unroll
    for (int kb = 0; kb < 9; kb++) {
      bf16x8 a0 = *(const bf16x8*)(ap0 + ((kb * 64 + g * 16) ^ swz0));
      bf16x8 a1 = *(const bf16x8*)(ap1 + ((kb * 64 + g * 16) ^ swz1));
      bf16x8 b0 = W1F[(kb * 8 + wc * 2 + 0) * 64 + lane];
      bf16x8 b1 = W1F[(kb * 8 + wc * 2 + 1) * 64 + lane];
      acc00 = MFMA16(a0, b0, acc00);
      acc01 = MFMA16(a0, b1, acc01);
      acc10 = MFMA16(a1, b0, acc10);
      acc11 = MFMA16(a1, b1, acc11);
    }
    __syncthreads();

    {
      const int col0 = wc * 32 + lq;
      const float s1v0 = SC[col0], c1v0 = SC[128 + col0];
      const float s1v1 = SC[col0 + 16], c1v1 = SC[128 + col0 + 16];
      const int xoff = wc * 64 + lq * 4;
#pragma unroll
      for (int j = 0; j < 4; j++) {
        int rowa = wr * 32 + 4 * g + j;
        unsigned int pA = cvtpk(fmaxf(acc00[j] * s1v0 + c1v0, 0.f),
                                fmaxf(acc01[j] * s1v1 + c1v1, 0.f));
        *(unsigned int*)(X1 + rowa * 256 + (xoff ^ ((rowa & 7) << 4))) = pA;
        int rowb = rowa + 16;
        unsigned int pB = cvtpk(fmaxf(acc10[j] * s1v0 + c1v0, 0.f),
                                fmaxf(acc11[j] * s1v1 + c1v1, 0.f));
        *(unsigned int*)(X1 + rowb * 256 + (xoff ^ ((rowb & 7) << 4))) = pB;
      }
    }
    __syncthreads();

    f32x4 acc2A = {0.f, 0.f, 0.f, 0.f}, acc2B = acc2A;
    {
      const int row = w2r * 16 + lq;
      const int swz = (row & 7) << 4;
      const char* xp = X1 + row * 256;
      bf16x8 a0 = *(const bf16x8*)(xp + ((0 * 64 + g * 16) ^ swz));
      acc2A = MFMA16(a0, w2g0, acc2A);
      acc2B = MFMA16(a0, w2h0, acc2B);
      bf16x8 a1 = *(const bf16x8*)(xp + ((1 * 64 + g * 16) ^ swz));
      acc2A = MFMA16(a1, w2g1, acc2A);
      acc2B = MFMA16(a1, w2h1, acc2B);
      bf16x8 a2 = *(const bf16x8*)(xp + ((2 * 64 + g * 16) ^ swz));
      acc2A = MFMA16(a2, w2g2, acc2A);
      acc2B = MFMA16(a2, w2h2, acc2B);
      bf16x8 a3 = *(const bf16x8*)(xp + ((3 * 64 + g * 16) ^ swz));
      acc2A = MFMA16(a3, w2g3, acc2A);
      acc2B = MFMA16(a3, w2h3, acc2B);
    }

    const int colA = w2c * 32 + lq, colB = colA + 16;
    const float s2A = SC[256 + colA], c2A = SC[320 + colA];
    const float s2B = SC[256 + colB], c2B = SC[320 + colB];
    const float w3A = SC[384 + colA], w3B = SC[384 + colB];
#pragma unroll
    for (int j = 0; j < 4; j++) {
      float vA = fmaxf(acc2A[j] * s2A + c2A, 0.f);
      float vB = fmaxf(acc2B[j] * s2B + c2B, 0.f);
      float p = vA * w3A + vB * w3B;
      p += __shfl_xor(p, 1);
      p += __shfl_xor(p, 2);
      p += __shfl_xor(p, 4);
      p += __shfl_xor(p, 8);
      if (lq == 0) l3[(w2r * 16 + 4 * g + j) * 2 + w2c] = p;
    }
    __syncthreads();

    WRITE_A_F();
    {
      int tn2 = t + 2 * grid;
      if (tn2 >= nblk) tn2 = t + grid < nblk ? t + grid : t;
      GATHER_NEXT_F(tn2);
    }
    if (tid < 128) {
      int e = (t << 7) + tid;
      if (e < E) out[e] = l3[tid * 2] + l3[tid * 2 + 1] + SC[448];
    }
    __syncthreads();
  }
}

extern "C" void kernel_launch(void* const* d_in, const int* in_sizes, int n_in,
                              void* d_out, int out_size, void* d_ws, size_t ws_size,
                              hipStream_t stream) {
  const float* z = (const float*)d_in[0];
  const int* ei = (const int*)d_in[1];
  const float* ctx = (const float*)d_in[2];
  const float* W1 = (const float*)d_in[3];
  const float* b1 = (const float*)d_in[4];
  const float* g1 = (const float*)d_in[5];
  const float* be1 = (const float*)d_in[6];
  const float* m1 = (const float*)d_in[7];
  const float* v1 = (const float*)d_in[8];
  const float* W2 = (const float*)d_in[9];
  const float* b2 = (const float*)d_in[10];
  const float* g2 = (const float*)d_in[11];
  const float* be2 = (const float*)d_in[12];
  const float* m2 = (const float*)d_in[13];
  const float* v2 = (const float*)d_in[14];
  const float* W3 = (const float*)d_in[15];
  const float* b3 = (const float*)d_in[16];
  float* out = (float*)d_out;
  const int E = out_size;

  unsigned short* w1f = (unsigned short*)d_ws;
  unsigned short* w2f = (unsigned short*)((char*)d_ws + 73728);
  float* sc = (float*)((char*)d_ws + 90112);

  prep_kernel<<<177, 256, 0, stream>>>(W1, W2, b1, g1, be1, m1, v1,
                                       b2, g2, be2, m2, v2, w1f, w2f, sc);

  const int nblk = (E + 127) >> 7;

  // Pick the W1-in-regs kernel only if the allocator granted it spill-free
  // (localSizeBytes == 0). Deterministic: attribute is a compile-time constant.
  hipFuncAttributes attr;
  bool use_r = false;
  if (hipFuncGetAttributes(&attr, (const void*)fused_kernel_r) == hipSuccess) {
    use_r = (attr.localSizeBytes < 16);
  }

  if (use_r) {
    (void)hipFuncSetAttribute((const void*)fused_kernel_r,
                              hipFuncAttributeMaxDynamicSharedMemorySize, R_LDS_TOTAL);
    fused_kernel_r<<<256, 512, R_LDS_TOTAL, stream>>>(z, ei, ctx, w1f, w2f, sc, W3, b3,
                                                      out, E, nblk);
  } else {
    (void)hipFuncSetAttribute((const void*)fused_kernel_f,
                              hipFuncAttributeMaxDynamicSharedMemorySize, F_LDS_TOTAL);
    fused_kernel_f<<<256, 1024, F_LDS_TOTAL, stream>>>(z, ei, ctx, w1f, w2f, sc, W3, b3,
                                                       out, E, nblk);
  }
}

// Round 11
// 137.075 us; speedup vs baseline: 2.8477x; 1.0008x over previous
//
#include <hip/hip_runtime.h>
#include <hip/hip_bf16.h>

typedef __attribute__((ext_vector_type(8))) short bf16x8;
typedef __attribute__((ext_vector_type(4))) float f32x4;
typedef __attribute__((ext_vector_type(4))) unsigned int u32x4;
typedef __attribute__((ext_vector_type(2))) unsigned int u32x2;
typedef __attribute__((ext_vector_type(2))) __bf16 bf16x2v;

#define EPS 1e-5f

__device__ inline unsigned short f2bf(float x) {  // RNE (prep kernel only; cold)
  unsigned int u = __builtin_bit_cast(unsigned int, x);
  unsigned int r = (u + 0x7FFFu + ((u >> 16) & 1u)) >> 16;
  return (unsigned short)r;
}

// hot-path pair pack: compiles to v_cvt_pk_bf16_f32 (1 VALU op; RNE)
__device__ inline unsigned int cvtpk(float a, float b) {
  bf16x2v v = {(__bf16)a, (__bf16)b};
  return __builtin_bit_cast(unsigned int, v);
}

// ---------------- prep: fold BN, pre-swizzle W1/W2 into MFMA fragment order ----------------
// ws layout: w1f bf16 [73728 B] | w2f bf16 [16384 B] | sc f32[384]
// W2 rows permuted: physical k-slot s holds logical row (s&96)|((s&1)<<4)|((s>>1)&15)
// — matches the packed x1 writes.
__global__ void prep_kernel(const float* __restrict__ W1, const float* __restrict__ W2,
                            const float* __restrict__ b1, const float* __restrict__ g1,
                            const float* __restrict__ be1, const float* __restrict__ m1,
                            const float* __restrict__ v1,
                            const float* __restrict__ b2, const float* __restrict__ g2,
                            const float* __restrict__ be2, const float* __restrict__ m2,
                            const float* __restrict__ v2,
                            unsigned short* __restrict__ w1f, unsigned short* __restrict__ w2f,
                            float* __restrict__ sc) {
  int t = blockIdx.x * 256 + threadIdx.x;
  if (t < 36864) {
    int j = t & 7, l = (t >> 3) & 63, f = t >> 9;
    int kb = f >> 3, nb = f & 7;
    int rk = kb * 32 + ((l >> 4) << 3) + j;
    int cn = (nb << 4) + (l & 15);
    w1f[t] = f2bf(W1[rk * 128 + cn]);
  } else if (t < 45056) {
    int o = t - 36864;
    int j = o & 7, l = (o >> 3) & 63, f = o >> 9;
    int kb = f >> 2, nb = f & 3;
    int s = kb * 32 + ((l >> 4) << 3) + j;                 // physical k-slot
    int rk = (s & 96) | ((s & 1) << 4) | ((s >> 1) & 15);  // logical W2 row
    int cn = (nb << 4) + (l & 15);
    w2f[o] = f2bf(W2[rk * 64 + cn]);
  } else if (t < 45184) {
    int j = t - 45056;
    float s = g1[j] * rsqrtf(v1[j] + EPS);
    sc[j] = s;
    sc[128 + j] = (b1[j] - m1[j]) * s + be1[j];
  } else if (t < 45248) {
    int j = t - 45184;
    float s = g2[j] * rsqrtf(v2[j] + EPS);
    sc[256 + j] = s;
    sc[320 + j] = (b2[j] - m2[j]) * s + be2[j];
  }
}

// ================= PRIMARY: 512 threads, W1 in regs, amdgpu_waves_per_eu(2,2) =================
// R5-R10 showed __launch_bounds__ 2nd-arg encodings all clamp arch VGPRs at <=128 and the
// W1-frag array spills. amdgpu_waves_per_eu(2,2) is the direct LLVM occupancy target:
// 2 waves/EU -> 512-reg file / 2 = 256 regs/wave budget. Demand ~190 fits. Host checks
// localSizeBytes and falls back to the proven f kernel (137 us) if the grant fails again.
// LDS map:
//   [0, 81920)        A-tile [128 rows x 640 B], XOR-swizzled
//   [81920, 114688)   x1 [128 rows x 256 B], XOR-swizzled, k-permuted (pairs packed)
//   [114688, 131072)  W2 frags (persistent)
//   [131072, 132096)  l3 f32[256]
#define R_X1_OFF 81920
#define R_W2_OFF 114688
#define R_L3_OFF 131072
#define R_LDS_TOTAL 132096

#define WRITE_A_R()                                                                              \
  do {                                                                                           \
    const int rswz_ = (sr & 7) << 4;                                                             \
    char* rowp_ = AR + sr * 640;                                                                 \
    u32x4 s0_ = {cvtpk(sv0[0], sv0[1]), cvtpk(sv0[2], sv0[3]), cvtpk(sv1[0], sv1[1]),            \
                 cvtpk(sv1[2], sv1[3])};                                                         \
    u32x4 s1_ = {cvtpk(sv2[0], sv2[1]), cvtpk(sv2[2], sv2[3]), cvtpk(sv3[0], sv3[1]),            \
                 cvtpk(sv3[2], sv3[3])};                                                         \
    u32x4 d0_ = {cvtpk(dv0[0], dv0[1]), cvtpk(dv0[2], dv0[3]), cvtpk(dv1[0], dv1[1]),            \
                 cvtpk(dv1[2], dv1[3])};                                                         \
    u32x4 d1_ = {cvtpk(dv2[0], dv2[1]), cvtpk(dv2[2], dv2[3]), cvtpk(dv3[0], dv3[1]),            \
                 cvtpk(dv3[2], dv3[3])};                                                         \
    u32x4 p0_ = {cvtpk(sv0[0] * dv0[0], sv0[1] * dv0[1]), cvtpk(sv0[2] * dv0[2], sv0[3] * dv0[3]),\
                 cvtpk(sv1[0] * dv1[0], sv1[1] * dv1[1]), cvtpk(sv1[2] * dv1[2], sv1[3] * dv1[3])};\
    u32x4 p1_ = {cvtpk(sv2[0] * dv2[0], sv2[1] * dv2[1]), cvtpk(sv2[2] * dv2[2], sv2[3] * dv2[3]),\
                 cvtpk(sv3[0] * dv3[0], sv3[1] * dv3[1]), cvtpk(sv3[2] * dv3[2], sv3[3] * dv3[3])};\
    u32x4 a0_ = {cvtpk(fabsf(sv0[0] - dv0[0]), fabsf(sv0[1] - dv0[1])),                          \
                 cvtpk(fabsf(sv0[2] - dv0[2]), fabsf(sv0[3] - dv0[3])),                          \
                 cvtpk(fabsf(sv1[0] - dv1[0]), fabsf(sv1[1] - dv1[1])),                          \
                 cvtpk(fabsf(sv1[2] - dv1[2]), fabsf(sv1[3] - dv1[3]))};                         \
    u32x4 a1_ = {cvtpk(fabsf(sv2[0] - dv2[0]), fabsf(sv2[1] - dv2[1])),                          \
                 cvtpk(fabsf(sv2[2] - dv2[2]), fabsf(sv2[3] - dv2[3])),                          \
                 cvtpk(fabsf(sv3[0] - dv3[0]), fabsf(sv3[1] - dv3[1])),                          \
                 cvtpk(fabsf(sv3[2] - dv3[2]), fabsf(sv3[3] - dv3[3]))};                         \
    u32x4 c0_ = {cvtpk(cv0[0], cv0[1]), cvtpk(cv0[2], cv0[3]), cvtpk(cv1[0], cv1[1]),            \
                 cvtpk(cv1[2], cv1[3])};                                                         \
    *(u32x4*)(rowp_ + ((sh * 32) ^ rswz_)) = s0_;                                                \
    *(u32x4*)(rowp_ + ((sh * 32 + 16) ^ rswz_)) = s1_;                                           \
    *(u32x4*)(rowp_ + ((128 + sh * 32) ^ rswz_)) = d0_;                                          \
    *(u32x4*)(rowp_ + ((128 + sh * 32 + 16) ^ rswz_)) = d1_;                                     \
    *(u32x4*)(rowp_ + ((256 + sh * 32) ^ rswz_)) = p0_;                                          \
    *(u32x4*)(rowp_ + ((256 + sh * 32 + 16) ^ rswz_)) = p1_;                                     \
    *(u32x4*)(rowp_ + ((384 + sh * 32) ^ rswz_)) = a0_;                                          \
    *(u32x4*)(rowp_ + ((384 + sh * 32 + 16) ^ rswz_)) = a1_;                                     \
    *(u32x4*)(rowp_ + ((512 + sh * 16) ^ rswz_)) = c0_;                                          \
  } while (0)

#define GATHER_NEXT_R(tg)                                                                        \
  do {                                                                                           \
    const f32x4* zs_ = (const f32x4*)(z + ((size_t)i0n * 64 + sh * 16));                         \
    sv0 = zs_[0]; sv1 = zs_[1]; sv2 = zs_[2]; sv3 = zs_[3];                                      \
    const f32x4* zd_ = (const f32x4*)(z + ((size_t)i1n * 64 + sh * 16));                         \
    dv0 = zd_[0]; dv1 = zd_[1]; dv2 = zd_[2]; dv3 = zd_[3];                                      \
    int eg_ = ((tg) << 7) + sr;                                                                  \
    int esg_ = eg_ < E ? eg_ : E - 1;                                                            \
    const f32x4* cx_ = (const f32x4*)(ctx + (size_t)esg_ * 32 + sh * 8);                         \
    cv0 = cx_[0]; cv1 = cx_[1];                                                                  \
    int tn_ = (tg) + grid;                                                                       \
    if (tn_ >= nblk) tn_ = (tg);                                                                 \
    int en_ = (tn_ << 7) + sr;                                                                   \
    int esn_ = en_ < E ? en_ : E - 1;                                                            \
    i0n = ei[esn_];                                                                              \
    i1n = ei[E + esn_];                                                                          \
  } while (0)

#define MFMA16(A, B, C) __builtin_amdgcn_mfma_f32_16x16x32_bf16((A), (B), (C), 0, 0, 0)

#define L1STEP_R(KB, BB0, BB1)                                                                   \
  do {                                                                                           \
    bf16x8 a0_ = *(const bf16x8*)(ap0 + (((KB) * 64 + g * 16) ^ aswz));                          \
    bf16x8 a1_ = *(const bf16x8*)(ap1 + (((KB) * 64 + g * 16) ^ aswz));                          \
    bf16x8 a2_ = *(const bf16x8*)(ap2 + (((KB) * 64 + g * 16) ^ aswz));                          \
    bf16x8 a3_ = *(const bf16x8*)(ap3 + (((KB) * 64 + g * 16) ^ aswz));                          \
    acc00 = MFMA16(a0_, BB0, acc00); acc01 = MFMA16(a0_, BB1, acc01);                            \
    acc10 = MFMA16(a1_, BB0, acc10); acc11 = MFMA16(a1_, BB1, acc11);                            \
    acc20 = MFMA16(a2_, BB0, acc20); acc21 = MFMA16(a2_, BB1, acc21);                            \
    acc30 = MFMA16(a3_, BB0, acc30); acc31 = MFMA16(a3_, BB1, acc31);                            \
  } while (0)

#define X1W_R(MF, ACA, ACB)                                                                      \
  do {                                                                                           \
    _Pragma("unroll")                                                                            \
    for (int j = 0; j < 4; j++) {                                                                \
      int row_ = wr * 64 + (MF) * 16 + 4 * g + j;                                                \
      unsigned int p_ = cvtpk(fmaxf(ACA[j] * s1v0 + c1v0, 0.f),                                  \
                              fmaxf(ACB[j] * s1v1 + c1v1, 0.f));                                 \
      *(unsigned int*)(X1 + row_ * 256 + (xoff ^ ((row_ & 7) << 4))) = p_;                       \
    }                                                                                            \
  } while (0)

#define L2STEP_R(KB)                                                                             \
  do {                                                                                           \
    bf16x8 xa_ = *(const bf16x8*)(xp0 + (((KB) * 64 + g * 16) ^ aswz));                          \
    bf16x8 xb_ = *(const bf16x8*)(xp1 + (((KB) * 64 + g * 16) ^ aswz));                          \
    bf16x8 bg_ = *(const bf16x8*)(W2L + (((KB) * 4 + w2c * 2 + 0) * 64 + lane) * 16);            \
    bf16x8 bh_ = *(const bf16x8*)(W2L + (((KB) * 4 + w2c * 2 + 1) * 64 + lane) * 16);            \
    acc2A0 = MFMA16(xa_, bg_, acc2A0); acc2A1 = MFMA16(xa_, bh_, acc2A1);                        \
    acc2B0 = MFMA16(xb_, bg_, acc2B0); acc2B1 = MFMA16(xb_, bh_, acc2B1);                        \
  } while (0)

__global__ __attribute__((amdgpu_flat_work_group_size(512, 512), amdgpu_waves_per_eu(2, 2)))
void fused_kernel_r(
    const float* __restrict__ z, const int* __restrict__ ei, const float* __restrict__ ctx,
    const unsigned short* __restrict__ w1f, const unsigned short* __restrict__ w2f,
    const float* __restrict__ sc, const float* __restrict__ w3, const float* __restrict__ b3,
    float* __restrict__ out, int E, int nblk) {
  extern __shared__ char lds[];
  char* AR = lds;
  char* X1 = lds + R_X1_OFF;
  char* W2L = lds + R_W2_OFF;
  float* l3 = (float*)(lds + R_L3_OFF);

  const int tid = threadIdx.x;
  const int lane = tid & 63, wave = tid >> 6;       // 8 waves
  const int g = lane >> 4, lq = lane & 15;
  const int wr = wave >> 2, wc = wave & 3;          // L1 grid 2x4: 64 rows x 32 cols per wave
  const int w2r = wave >> 1, w2c = wave & 1;        // L2 grid 4x2: 32 rows x 32 cols per wave
  const int sr = tid >> 2, sh = tid & 3;            // staging: 4 threads per edge
  const int grid = gridDim.x;
  const int aswz = (lq & 7) << 4;

  // ---- stage W2 frags into LDS (16 KB, persistent) ----
  ((f32x4*)W2L)[tid] = ((const f32x4*)w2f)[tid];
  ((f32x4*)W2L)[512 + tid] = ((const f32x4*)w2f)[512 + tid];

  // ---- hoist BN/W3 constants into registers (global loads, once) ----
  const int col0 = wc * 32 + lq;
  const float s1v0 = sc[col0], c1v0 = sc[128 + col0];
  const float s1v1 = sc[col0 + 16], c1v1 = sc[128 + col0 + 16];
  const int colA = w2c * 32 + lq;
  const float s2A = sc[256 + colA], c2A = sc[320 + colA];
  const float s2B = sc[256 + colA + 16], c2B = sc[320 + colA + 16];
  const float w3A = w3[colA], w3B = w3[colA + 16];
  const float b3v = b3[0];
  const int xoff = wc * 64 + lq * 4;  // packed x1 pair slots (perm matches prep W2)

  // ---- persistent W1 fragments in registers (72 VGPR): nf = wc*2 + {0,1}, kb 0..8 ----
  const bf16x8* W1G = (const bf16x8*)w1f;
  bf16x8 w1r0 = W1G[(0 * 8 + wc * 2 + 0) * 64 + lane], w1s0 = W1G[(0 * 8 + wc * 2 + 1) * 64 + lane];
  bf16x8 w1r1 = W1G[(1 * 8 + wc * 2 + 0) * 64 + lane], w1s1 = W1G[(1 * 8 + wc * 2 + 1) * 64 + lane];
  bf16x8 w1r2 = W1G[(2 * 8 + wc * 2 + 0) * 64 + lane], w1s2 = W1G[(2 * 8 + wc * 2 + 1) * 64 + lane];
  bf16x8 w1r3 = W1G[(3 * 8 + wc * 2 + 0) * 64 + lane], w1s3 = W1G[(3 * 8 + wc * 2 + 1) * 64 + lane];
  bf16x8 w1r4 = W1G[(4 * 8 + wc * 2 + 0) * 64 + lane], w1s4 = W1G[(4 * 8 + wc * 2 + 1) * 64 + lane];
  bf16x8 w1r5 = W1G[(5 * 8 + wc * 2 + 0) * 64 + lane], w1s5 = W1G[(5 * 8 + wc * 2 + 1) * 64 + lane];
  bf16x8 w1r6 = W1G[(6 * 8 + wc * 2 + 0) * 64 + lane], w1s6 = W1G[(6 * 8 + wc * 2 + 1) * 64 + lane];
  bf16x8 w1r7 = W1G[(7 * 8 + wc * 2 + 0) * 64 + lane], w1s7 = W1G[(7 * 8 + wc * 2 + 1) * 64 + lane];
  bf16x8 w1r8 = W1G[(8 * 8 + wc * 2 + 0) * 64 + lane], w1s8 = W1G[(8 * 8 + wc * 2 + 1) * 64 + lane];

  f32x4 sv0, sv1, sv2, sv3, dv0, dv1, dv2, dv3, cv0, cv1;
  int i0n, i1n;
  int t = blockIdx.x;

  // ---- prologue: gather tile t, write A(t), gather t+1, prefetch ei t+2 ----
  {
    int e = (t << 7) + sr;
    int es = e < E ? e : E - 1;
    int a0 = ei[es], a1 = ei[E + es];
    const f32x4* cx = (const f32x4*)(ctx + (size_t)es * 32 + sh * 8);
    cv0 = cx[0]; cv1 = cx[1];
    const f32x4* zs = (const f32x4*)(z + ((size_t)a0 * 64 + sh * 16));
    sv0 = zs[0]; sv1 = zs[1]; sv2 = zs[2]; sv3 = zs[3];
    const f32x4* zd = (const f32x4*)(z + ((size_t)a1 * 64 + sh * 16));
    dv0 = zd[0]; dv1 = zd[1]; dv2 = zd[2]; dv3 = zd[3];
    int tn = t + grid;
    if (tn >= nblk) tn = t;
    int en = (tn << 7) + sr;
    int esn = en < E ? en : E - 1;
    i0n = ei[esn];
    i1n = ei[E + esn];
  }
  WRITE_A_R();
  {
    int tn = t + grid;
    if (tn >= nblk) tn = t;
    GATHER_NEXT_R(tn);
  }
  __syncthreads();  // A(t) + W2L visible

  for (; t < nblk; t += grid) {
    // ---- layer 1: A[128x288] @ W1[288x128]; wave tile 64x32 (4x2 frags), W1 from regs ----
    f32x4 acc00 = {0.f, 0.f, 0.f, 0.f}, acc01 = acc00, acc10 = acc00, acc11 = acc00;
    f32x4 acc20 = acc00, acc21 = acc00, acc30 = acc00, acc31 = acc00;
    const char* ap0 = AR + (wr * 64 + 0 * 16 + lq) * 640;
    const char* ap1 = AR + (wr * 64 + 1 * 16 + lq) * 640;
    const char* ap2 = AR + (wr * 64 + 2 * 16 + lq) * 640;
    const char* ap3 = AR + (wr * 64 + 3 * 16 + lq) * 640;
    L1STEP_R(0, w1r0, w1s0);
    L1STEP_R(1, w1r1, w1s1);
    L1STEP_R(2, w1r2, w1s2);
    L1STEP_R(3, w1r3, w1s3);
    L1STEP_R(4, w1r4, w1s4);
    L1STEP_R(5, w1r5, w1s5);
    L1STEP_R(6, w1r6, w1s6);
    L1STEP_R(7, w1r7, w1s7);
    L1STEP_R(8, w1r8, w1s8);
    __syncthreads();  // all waves done reading A(t)

    // ---- phase 2: A-write(t+1), issue gathers(t+2), x1-write(t) ----
    WRITE_A_R();
    {
      int tn2 = t + 2 * grid;
      if (tn2 >= nblk) tn2 = t + grid < nblk ? t + grid : t;
      GATHER_NEXT_R(tn2);
    }
    X1W_R(0, acc00, acc01);
    X1W_R(1, acc10, acc11);
    X1W_R(2, acc20, acc21);
    X1W_R(3, acc30, acc31);
    __syncthreads();  // x1(t) + A(t+1) visible

    // ---- layer 2: x1[128x128] @ W2[128x64]; wave tile 32x32, W2 from LDS ----
    f32x4 acc2A0 = {0.f, 0.f, 0.f, 0.f}, acc2A1 = acc2A0, acc2B0 = acc2A0, acc2B1 = acc2A0;
    const char* xp0 = X1 + (w2r * 32 + lq) * 256;
    const char* xp1 = xp0 + 4096;
    L2STEP_R(0);
    L2STEP_R(1);
    L2STEP_R(2);
    L2STEP_R(3);

    // ---- layer 3: bn+relu, dot w3, 16-lane shfl reduce ----
    {
#pragma unroll
      for (int j = 0; j < 4; j++) {
        float pA = fmaxf(acc2A0[j] * s2A + c2A, 0.f) * w3A +
                   fmaxf(acc2A1[j] * s2B + c2B, 0.f) * w3B;
        pA += __shfl_xor(pA, 1);
        pA += __shfl_xor(pA, 2);
        pA += __shfl_xor(pA, 4);
        pA += __shfl_xor(pA, 8);
        float pB = fmaxf(acc2B0[j] * s2A + c2A, 0.f) * w3A +
                   fmaxf(acc2B1[j] * s2B + c2B, 0.f) * w3B;
        pB += __shfl_xor(pB, 1);
        pB += __shfl_xor(pB, 2);
        pB += __shfl_xor(pB, 4);
        pB += __shfl_xor(pB, 8);
        if (lq == 0) {
          l3[(w2r * 32 + 4 * g + j) * 2 + w2c] = pA;
          l3[(w2r * 32 + 16 + 4 * g + j) * 2 + w2c] = pB;
        }
      }
    }
    __syncthreads();  // l3 visible; all x1 reads done

    if (tid < 128) {
      int e = (t << 7) + tid;
      if (e < E) out[e] = l3[tid * 2] + l3[tid * 2 + 1] + b3v;
    }
  }
}

// ================= FALLBACK: R6 kernel verbatim (137.7 us, no spill) =================
// 1024 threads, W1 in LDS, W2 in regs (32 VGPR), SC in LDS, X1 aliases A region.
#define F_SC_OFF 73728
#define F_A_OFF 75776
#define F_L3_OFF 157696
#define F_LDS_TOTAL 158720

#define WRITE_A_F()                                                                              \
  do {                                                                                           \
    const int rswz_ = (sr & 7) << 4;                                                             \
    char* rowp_ = AR + sr * 640;                                                                 \
    u32x4 ps_ = {cvtpk(sv0[0], sv0[1]), cvtpk(sv0[2], sv0[3]), cvtpk(sv1[0], sv1[1]),            \
                 cvtpk(sv1[2], sv1[3])};                                                         \
    u32x4 pd_ = {cvtpk(dv0[0], dv0[1]), cvtpk(dv0[2], dv0[3]), cvtpk(dv1[0], dv1[1]),            \
                 cvtpk(dv1[2], dv1[3])};                                                         \
    u32x4 pp_ = {cvtpk(sv0[0] * dv0[0], sv0[1] * dv0[1]), cvtpk(sv0[2] * dv0[2], sv0[3] * dv0[3]),\
                 cvtpk(sv1[0] * dv1[0], sv1[1] * dv1[1]), cvtpk(sv1[2] * dv1[2], sv1[3] * dv1[3])};\
    u32x4 pa_ = {cvtpk(fabsf(sv0[0] - dv0[0]), fabsf(sv0[1] - dv0[1])),                          \
                 cvtpk(fabsf(sv0[2] - dv0[2]), fabsf(sv0[3] - dv0[3])),                          \
                 cvtpk(fabsf(sv1[0] - dv1[0]), fabsf(sv1[1] - dv1[1])),                          \
                 cvtpk(fabsf(sv1[2] - dv1[2]), fabsf(sv1[3] - dv1[3]))};                         \
    u32x2 pc_ = {cvtpk(cv[0], cv[1]), cvtpk(cv[2], cv[3])};                                      \
    *(u32x4*)(rowp_ + ((sh * 16) ^ rswz_)) = ps_;                                                \
    *(u32x4*)(rowp_ + ((128 + sh * 16) ^ rswz_)) = pd_;                                          \
    *(u32x4*)(rowp_ + ((256 + sh * 16) ^ rswz_)) = pp_;                                          \
    *(u32x4*)(rowp_ + ((384 + sh * 16) ^ rswz_)) = pa_;                                          \
    *(u32x2*)(rowp_ + 512 + ((sh * 8) ^ rswz_)) = pc_;                                           \
  } while (0)

#define GATHER_NEXT_F(tg)                                                                        \
  do {                                                                                           \
    const f32x4* zs_ = (const f32x4*)(z + ((size_t)i0n * 64 + sh * 8));                          \
    sv0 = zs_[0];                                                                                \
    sv1 = zs_[1];                                                                                \
    const f32x4* zd_ = (const f32x4*)(z + ((size_t)i1n * 64 + sh * 8));                          \
    dv0 = zd_[0];                                                                                \
    dv1 = zd_[1];                                                                                \
    int eg_ = ((tg) << 7) + sr;                                                                  \
    int esg_ = eg_ < E ? eg_ : E - 1;                                                            \
    cv = *(const f32x4*)(ctx + (size_t)esg_ * 32 + sh * 4);                                      \
    int tn_ = (tg) + grid;                                                                       \
    if (tn_ >= nblk) tn_ = (tg);                                                                 \
    int en_ = (tn_ << 7) + sr;                                                                   \
    int esn_ = en_ < E ? en_ : E - 1;                                                            \
    i0n = ei[esn_];                                                                              \
    i1n = ei[E + esn_];                                                                          \
  } while (0)

__global__ __launch_bounds__(1024, 4) void fused_kernel_f(
    const float* __restrict__ z, const int* __restrict__ ei, const float* __restrict__ ctx,
    const unsigned short* __restrict__ w1f, const unsigned short* __restrict__ w2f,
    const float* __restrict__ sc, const float* __restrict__ w3, const float* __restrict__ b3,
    float* __restrict__ out, int E, int nblk) {
  extern __shared__ char lds[];
  char* W1L = lds;
  float* SC = (float*)(lds + F_SC_OFF);
  char* AR = lds + F_A_OFF;
  char* X1 = lds + F_A_OFF;  // alias: x1 overwrites A-head after L1 reads complete
  float* l3 = (float*)(lds + F_L3_OFF);

  const int tid = threadIdx.x;
  const int lane = tid & 63, wave = tid >> 6;
  const int g = lane >> 4, lq = lane & 15;
  const int wr = wave >> 2, wc = wave & 3;   // L1 grid 4x4
  const int w2r = wave >> 1, w2c = wave & 1; // L2 grid 8x2
  const int sr = tid >> 3, sh = tid & 7;     // staging: 8 threads per edge
  const int grid = gridDim.x;

  {
    const f32x4* s = (const f32x4*)w1f;
    f32x4* d = (f32x4*)W1L;
#pragma unroll
    for (int i = 0; i < 4; i++) d[i * 1024 + tid] = s[i * 1024 + tid];
    if (tid < 512) d[4096 + tid] = s[4096 + tid];
    if (tid < 128) {
      SC[tid] = sc[tid];
      SC[128 + tid] = sc[128 + tid];
    } else if (tid < 192) {
      int j = tid - 128;
      SC[256 + j] = sc[256 + j];
      SC[320 + j] = sc[320 + j];
      SC[384 + j] = w3[j];
    } else if (tid == 192) {
      SC[448] = b3[0];
    }
  }

  bf16x8 w2g0, w2g1, w2g2, w2g3, w2h0, w2h1, w2h2, w2h3;
  {
    const bf16x8* W2G = (const bf16x8*)w2f;
    w2g0 = W2G[(0 * 4 + w2c * 2 + 0) * 64 + lane];
    w2h0 = W2G[(0 * 4 + w2c * 2 + 1) * 64 + lane];
    w2g1 = W2G[(1 * 4 + w2c * 2 + 0) * 64 + lane];
    w2h1 = W2G[(1 * 4 + w2c * 2 + 1) * 64 + lane];
    w2g2 = W2G[(2 * 4 + w2c * 2 + 0) * 64 + lane];
    w2h2 = W2G[(2 * 4 + w2c * 2 + 1) * 64 + lane];
    w2g3 = W2G[(3 * 4 + w2c * 2 + 0) * 64 + lane];
    w2h3 = W2G[(3 * 4 + w2c * 2 + 1) * 64 + lane];
  }

  f32x4 sv0, sv1, dv0, dv1, cv;
  int i0n, i1n;
  int t = blockIdx.x;

  {
    int e = (t << 7) + sr;
    int es = e < E ? e : E - 1;
    int a0 = ei[es], a1 = ei[E + es];
    cv = *(const f32x4*)(ctx + (size_t)es * 32 + sh * 4);
    const f32x4* zs = (const f32x4*)(z + ((size_t)a0 * 64 + sh * 8));
    sv0 = zs[0];
    sv1 = zs[1];
    const f32x4* zd = (const f32x4*)(z + ((size_t)a1 * 64 + sh * 8));
    dv0 = zd[0];
    dv1 = zd[1];
    int tn = t + grid;
    if (tn >= nblk) tn = t;
    int en = (tn << 7) + sr;
    int esn = en < E ? en : E - 1;
    i0n = ei[esn];
    i1n = ei[E + esn];
  }
  WRITE_A_F();
  {
    int tn = t + grid;
    if (tn >= nblk) tn = t;
    GATHER_NEXT_F(tn);
  }
  __syncthreads();

  for (; t < nblk; t += grid) {
    f32x4 acc00 = {0.f, 0.f, 0.f, 0.f}, acc01 = acc00, acc10 = acc00, acc11 = acc00;
    const bf16x8* W1F = (const bf16x8*)W1L;
    const int row0 = wr * 32 + lq, row1 = row0 + 16;
    const int swz0 = (row0 & 7) << 4, swz1 = (row1 & 7) << 4;
    const char* ap0 = AR + row0 * 640;
    const char* ap1 = AR + row1 * 640;
#pragma unroll
    for (int kb = 0; kb < 9; kb++) {
      bf16x8 a0 = *(const bf16x8*)(ap0 + ((kb * 64 + g * 16) ^ swz0));
      bf16x8 a1 = *(const bf16x8*)(ap1 + ((kb * 64 + g * 16) ^ swz1));
      bf16x8 b0 = W1F[(kb * 8 + wc * 2 + 0) * 64 + lane];
      bf16x8 b1 = W1F[(kb * 8 + wc * 2 + 1) * 64 + lane];
      acc00 = MFMA16(a0, b0, acc00);
      acc01 = MFMA16(a0, b1, acc01);
      acc10 = MFMA16(a1, b0, acc10);
      acc11 = MFMA16(a1, b1, acc11);
    }
    __syncthreads();

    {
      const int col0 = wc * 32 + lq;
      const float s1v0 = SC[col0], c1v0 = SC[128 + col0];
      const float s1v1 = SC[col0 + 16], c1v1 = SC[128 + col0 + 16];
      const int xoff = wc * 64 + lq * 4;
#pragma unroll
      for (int j = 0; j < 4; j++) {
        int rowa = wr * 32 + 4 * g + j;
        unsigned int pA = cvtpk(fmaxf(acc00[j] * s1v0 + c1v0, 0.f),
                                fmaxf(acc01[j] * s1v1 + c1v1, 0.f));
        *(unsigned int*)(X1 + rowa * 256 + (xoff ^ ((rowa & 7) << 4))) = pA;
        int rowb = rowa + 16;
        unsigned int pB = cvtpk(fmaxf(acc10[j] * s1v0 + c1v0, 0.f),
                                fmaxf(acc11[j] * s1v1 + c1v1, 0.f));
        *(unsigned int*)(X1 + rowb * 256 + (xoff ^ ((rowb & 7) << 4))) = pB;
      }
    }
    __syncthreads();

    f32x4 acc2A = {0.f, 0.f, 0.f, 0.f}, acc2B = acc2A;
    {
      const int row = w2r * 16 + lq;
      const int swz = (row & 7) << 4;
      const char* xp = X1 + row * 256;
      bf16x8 a0 = *(const bf16x8*)(xp + ((0 * 64 + g * 16) ^ swz));
      acc2A = MFMA16(a0, w2g0, acc2A);
      acc2B = MFMA16(a0, w2h0, acc2B);
      bf16x8 a1 = *(const bf16x8*)(xp + ((1 * 64 + g * 16) ^ swz));
      acc2A = MFMA16(a1, w2g1, acc2A);
      acc2B = MFMA16(a1, w2h1, acc2B);
      bf16x8 a2 = *(const bf16x8*)(xp + ((2 * 64 + g * 16) ^ swz));
      acc2A = MFMA16(a2, w2g2, acc2A);
      acc2B = MFMA16(a2, w2h2, acc2B);
      bf16x8 a3 = *(const bf16x8*)(xp + ((3 * 64 + g * 16) ^ swz));
      acc2A = MFMA16(a3, w2g3, acc2A);
      acc2B = MFMA16(a3, w2h3, acc2B);
    }

    const int colA = w2c * 32 + lq, colB = colA + 16;
    const float s2A = SC[256 + colA], c2A = SC[320 + colA];
    const float s2B = SC[256 + colB], c2B = SC[320 + colB];
    const float w3A = SC[384 + colA], w3B = SC[384 + colB];
#pragma unroll
    for (int j = 0; j < 4; j++) {
      float vA = fmaxf(acc2A[j] * s2A + c2A, 0.f);
      float vB = fmaxf(acc2B[j] * s2B + c2B, 0.f);
      float p = vA * w3A + vB * w3B;
      p += __shfl_xor(p, 1);
      p += __shfl_xor(p, 2);
      p += __shfl_xor(p, 4);
      p += __shfl_xor(p, 8);
      if (lq == 0) l3[(w2r * 16 + 4 * g + j) * 2 + w2c] = p;
    }
    __syncthreads();

    WRITE_A_F();
    {
      int tn2 = t + 2 * grid;
      if (tn2 >= nblk) tn2 = t + grid < nblk ? t + grid : t;
      GATHER_NEXT_F(tn2);
    }
    if (tid < 128) {
      int e = (t << 7) + tid;
      if (e < E) out[e] = l3[tid * 2] + l3[tid * 2 + 1] + SC[448];
    }
    __syncthreads();
  }
}

extern "C" void kernel_launch(void* const* d_in, const int* in_sizes, int n_in,
                              void* d_out, int out_size, void* d_ws, size_t ws_size,
                              hipStream_t stream) {
  const float* z = (const float*)d_in[0];
  const int* ei = (const int*)d_in[1];
  const float* ctx = (const float*)d_in[2];
  const float* W1 = (const float*)d_in[3];
  const float* b1 = (const float*)d_in[4];
  const float* g1 = (const float*)d_in[5];
  const float* be1 = (const float*)d_in[6];
  const float* m1 = (const float*)d_in[7];
  const float* v1 = (const float*)d_in[8];
  const float* W2 = (const float*)d_in[9];
  const float* b2 = (const float*)d_in[10];
  const float* g2 = (const float*)d_in[11];
  const float* be2 = (const float*)d_in[12];
  const float* m2 = (const float*)d_in[13];
  const float* v2 = (const float*)d_in[14];
  const float* W3 = (const float*)d_in[15];
  const float* b3 = (const float*)d_in[16];
  float* out = (float*)d_out;
  const int E = out_size;

  unsigned short* w1f = (unsigned short*)d_ws;
  unsigned short* w2f = (unsigned short*)((char*)d_ws + 73728);
  float* sc = (float*)((char*)d_ws + 90112);

  prep_kernel<<<177, 256, 0, stream>>>(W1, W2, b1, g1, be1, m1, v1,
                                       b2, g2, be2, m2, v2, w1f, w2f, sc);

  const int nblk = (E + 127) >> 7;

  // Pick the W1-in-regs kernel only if the allocator granted it spill-free
  // (localSizeBytes == 0). Deterministic: attribute is a compile-time constant.
  hipFuncAttributes attr;
  bool use_r = false;
  if (hipFuncGetAttributes(&attr, (const void*)fused_kernel_r) == hipSuccess) {
    use_r = (attr.localSizeBytes < 16);
  }

  if (use_r) {
    (void)hipFuncSetAttribute((const void*)fused_kernel_r,
                              hipFuncAttributeMaxDynamicSharedMemorySize, R_LDS_TOTAL);
    fused_kernel_r<<<256, 512, R_LDS_TOTAL, stream>>>(z, ei, ctx, w1f, w2f, sc, W3, b3,
                                                      out, E, nblk);
  } else {
    (void)hipFuncSetAttribute((const void*)fused_kernel_f,
                              hipFuncAttributeMaxDynamicSharedMemorySize, F_LDS_TOTAL);
    fused_kernel_f<<<256, 1024, F_LDS_TOTAL, stream>>>(z, ei, ctx, w1f, w2f, sc, W3, b3,
                                                       out, E, nblk);
  }
}